// Round 4
// baseline (657.051 us; speedup 1.0000x reference)
//
#include <hip/hip_runtime.h>

// Problem constants
#define NTOK 343   // tokens per window (7*7*7)
#define NPAD 352   // 22 * 16
#define CEMB 192
#define NH   6
#define HD   32
#define NB   256
#define NWIN 64

typedef __attribute__((ext_vector_type(8))) short short8;   // 8 x bf16 bits
typedef __attribute__((ext_vector_type(4))) float f32x4;

__device__ __forceinline__ unsigned short f2bf(float f) {
    unsigned int u = __builtin_bit_cast(unsigned int, f);
    u += 0x7fffu + ((u >> 16) & 1u);          // round-to-nearest-even
    return (unsigned short)(u >> 16);
}
__device__ __forceinline__ float bf2f(unsigned short h) {
    unsigned int u = ((unsigned int)h) << 16;
    return __builtin_bit_cast(float, u);
}
__device__ __forceinline__ short8 pack8(float4 f0, float4 f1) {
    short8 r;
    r[0] = (short)f2bf(f0.x); r[1] = (short)f2bf(f0.y);
    r[2] = (short)f2bf(f0.z); r[3] = (short)f2bf(f0.w);
    r[4] = (short)f2bf(f1.x); r[5] = (short)f2bf(f1.y);
    r[6] = (short)f2bf(f1.z); r[7] = (short)f2bf(f1.w);
    return r;
}

// ---------------- prep: weights -> bf16 (scale folded into qw) ----------------
__global__ void prep_weights(const float* __restrict__ qw, const float* __restrict__ kvw,
                             const float* __restrict__ pw,
                             unsigned short* __restrict__ qwb, unsigned short* __restrict__ kvwb,
                             unsigned short* __restrict__ pwb) {
    const float scale = 0.17677669529663689f;   // 32^-0.5 folded into Q weights
    int idx = blockIdx.x * 256 + threadIdx.x;
    if (idx < 36864)        qwb[idx] = f2bf(qw[idx] * scale);
    else if (idx < 110592)  kvwb[idx - 36864] = f2bf(kvw[idx - 36864]);
    else if (idx < 147456)  pwb[idx - 110592] = f2bf(pw[idx - 110592]);
}

// ---------------- prep: biasT[h][key][q] (bf16, padded to 352x352) ----------------
__global__ void prep_biasT(const float* __restrict__ table, const int* __restrict__ rel,
                           unsigned short* __restrict__ biasT) {
    __shared__ int sidx[32 * 33];
    int bid = blockIdx.x;                  // 121 blocks: kt*11 + qt
    int kt = bid / 11, qt = bid - kt * 11;
    int k0 = kt * 32, q0 = qt * 32;
    for (int e = threadIdx.x; e < 1024; e += 256) {
        int i = e >> 5, j = e & 31;        // i: q-local, j: key-local
        int q = q0 + i, k = k0 + j;
        sidx[i * 33 + j] = (q < NTOK && k < NTOK) ? rel[q * NTOK + k] : -1;
    }
    __syncthreads();
    for (int h = 0; h < NH; h++) {
        for (int e = threadIdx.x; e < 1024; e += 256) {
            int kk = e >> 5, qq = e & 31;
            int idx = sidx[qq * 33 + kk];
            float v = (idx >= 0) ? table[idx * NH + h] : 0.f;
            biasT[((size_t)h * NPAD + (k0 + kk)) * NPAD + (q0 + qq)] = f2bf(v);
        }
    }
}

// ---------------- prep: maskT[w][key][q] (bf16, padded) ----------------
__global__ void prep_maskT(const float* __restrict__ mask, unsigned short* __restrict__ maskT) {
    __shared__ float sm[32 * 33];
    int bid = blockIdx.x;                  // 64*121 blocks
    int w = bid / 121;
    int rem = bid - w * 121;
    int kt = rem / 11, qt = rem - kt * 11;
    int k0 = kt * 32, q0 = qt * 32;
    for (int e = threadIdx.x; e < 1024; e += 256) {
        int i = e >> 5, j = e & 31;        // i: q-local, j: key-local
        int q = q0 + i, k = k0 + j;
        sm[i * 33 + j] = (q < NTOK && k < NTOK) ? mask[((size_t)w * NTOK + q) * NTOK + k] : 0.f;
    }
    __syncthreads();
    for (int e = threadIdx.x; e < 1024; e += 256) {
        int kk = e >> 5, qq = e & 31;
        maskT[((size_t)w * NPAD + (k0 + kk)) * NPAD + (q0 + qq)] = f2bf(sm[qq * 33 + kk]);
    }
}

// ---------------- QKV projection GEMM (v4: exec-safe transpose) ----------------
// Grid: (b, o in {Q,K,V}, half). 256 threads = 4 waves; wave handles up to 3
// m-tiles of its half (11 m-tiles per half).
// A loads: all 12 float4 (6 kc chunks) issued before MFMAs -> 12-deep MLP.
// Stores: V packs 4 consecutive m per lane (ushort4); Q/K do a 4x4 cross-lane
// transpose via select-BEFORE-shuffle butterflies (all lanes execute every
// shfl_xor unconditionally — no convergent-op-in-divergent-ternary hazard).
__global__ __launch_bounds__(256, 3)
void qkv_kernel(const float* __restrict__ x_in, const float* __restrict__ x_cross,
                const unsigned short* __restrict__ qwb, const unsigned short* __restrict__ kvwb,
                unsigned short* __restrict__ Qb, unsigned short* __restrict__ Kb,
                unsigned short* __restrict__ Vtb) {
    const int tid = threadIdx.x;
    const int wave = tid >> 6, lane = tid & 63;
    const int quad = lane >> 4, l16 = lane & 15;
    const int s4 = lane & 3, g4 = (l16 >> 2);
    const bool lo1 = (s4 & 1) != 0, lo2 = (s4 & 2) != 0;
    const int bx = blockIdx.x;
    const int b = bx / 6;
    const int rem = bx - b * 6;
    const int o = rem >> 1, half = rem & 1;
    const float* xsrc = (o == 0) ? x_in : x_cross;
    const unsigned short* wsrc = (o == 0) ? qwb : (o == 1 ? kvwb : (kvwb + 192 * CEMB));
    const f32x4 zero4 = {0.f, 0.f, 0.f, 0.f};
    const float4 fz4 = {0.f, 0.f, 0.f, 0.f};

    for (int mi = 0; mi < 3; mi++) {
        int mloc = wave + (mi << 2);
        if (mloc >= 11) continue;          // wave-uniform
        int mtg = half * 11 + mloc;        // global m-tile 0..21
        int row = mtg * 16 + l16;
        bool valid = row < NTOK;
        const float* xp = xsrc + ((size_t)b * NTOK + row) * CEMB + (quad << 3);

        // batch all A loads (12 float4, 6 kc chunks)
        float4 ra[12];
#pragma unroll
        for (int kc = 0; kc < 6; kc++) {
            ra[2 * kc]     = valid ? *(const float4*)(xp + kc * 32)     : fz4;
            ra[2 * kc + 1] = valid ? *(const float4*)(xp + kc * 32 + 4) : fz4;
        }
        short8 a[6];
#pragma unroll
        for (int kc = 0; kc < 6; kc++) a[kc] = pack8(ra[2 * kc], ra[2 * kc + 1]);

        f32x4 acc[12];
#pragma unroll
        for (int nt = 0; nt < 12; nt++) acc[nt] = zero4;
#pragma unroll
        for (int kc = 0; kc < 6; kc++) {
            short8 bfr[12];
#pragma unroll
            for (int nt = 0; nt < 12; nt++)
                bfr[nt] = *(const short8*)(wsrc + ((size_t)(nt * 16 + l16)) * CEMB + kc * 32 + (quad << 3));
#pragma unroll
            for (int nt = 0; nt < 12; nt++)
                acc[nt] = __builtin_amdgcn_mfma_f32_16x16x32_bf16(a[kc], bfr[nt], acc[nt], 0, 0, 0);
        }

        if (o < 2) {
            // 4x4 transpose within groups of 4 lanes (exec-safe), then ushort4 stores.
            unsigned short* dst = (o == 0 ? Qb : Kb) + (size_t)b * NPAD * CEMB;
            int mrow = mtg * 16 + (quad << 2) + s4;
#pragma unroll
            for (int nt = 0; nt < 12; nt++) {
                float v0 = acc[nt][0], v1 = acc[nt][1], v2 = acc[nt][2], v3 = acc[nt][3];
                // stage 1: xor-1 exchange (select data first, shuffle unconditionally)
                float sA = lo1 ? v0 : v1;          // odd sends v0, even sends v1
                float sB = lo1 ? v2 : v3;
                float rA = __shfl_xor(sA, 1);
                float rB = __shfl_xor(sB, 1);
                float u0 = lo1 ? rA : v0;
                float u1 = lo1 ? v1 : rA;
                float u2 = lo1 ? rB : v2;
                float u3 = lo1 ? v3 : rB;
                // stage 2: xor-2 exchange
                float sC = lo2 ? u0 : u2;
                float sD = lo2 ? u1 : u3;
                float rC = __shfl_xor(sC, 2);
                float rD = __shfl_xor(sD, 2);
                float w0 = lo2 ? rC : u0;
                float w1 = lo2 ? rD : u1;
                float w2 = lo2 ? u2 : rC;
                float w3 = lo2 ? u3 : rD;
                ushort4 pk;
                pk.x = f2bf(w0); pk.y = f2bf(w1); pk.z = f2bf(w2); pk.w = f2bf(w3);
                *(ushort4*)(dst + (size_t)mrow * CEMB + nt * 16 + (g4 << 2)) = pk;
            }
        } else {
            int m0 = mtg * 16 + (quad << 2);
#pragma unroll
            for (int nt = 0; nt < 12; nt++) {
                int h = nt >> 1, d = ((nt & 1) << 4) + l16;
                ushort4 pk;
                pk.x = f2bf(acc[nt][0]); pk.y = f2bf(acc[nt][1]);
                pk.z = f2bf(acc[nt][2]); pk.w = f2bf(acc[nt][3]);
                *(ushort4*)(Vtb + (((size_t)b * NH + h) * 32 + d) * 360 + m0) = pk;
            }
        }
    }
}

// ---------------- fused attention per (window b, head h) ----------------
// LDS (dynamic, 63488 B): Ks[352][40] @0 (28160), Vt[32][360] @28160 (23040),
// P strips 8 x [16][48] @51200 (12288). 2 blocks/CU.
// Streaming PV with bias/mask loads software-pipelined one chunk ahead.
__global__ __launch_bounds__(512, 4)
void attn_kernel(const unsigned short* __restrict__ Qb, const unsigned short* __restrict__ Kb,
                 const unsigned short* __restrict__ Vtb,
                 const unsigned short* __restrict__ biasT, const unsigned short* __restrict__ maskT,
                 unsigned short* __restrict__ attnb) {
    extern __shared__ char smem[];
    unsigned short* Ks = (unsigned short*)smem;             // [352][40]
    unsigned short* Vt = (unsigned short*)(smem + 28160);   // [32][360]
    unsigned short* Pb = (unsigned short*)(smem + 51200);   // 8 x [16][48]

    const int tid = threadIdx.x;
    const int wave = tid >> 6, lane = tid & 63;
    const int quad = lane >> 4, l16 = lane & 15;
    const int b = blockIdx.x / NH, h = blockIdx.x - (blockIdx.x / NH) * NH;
    const f32x4 zero4 = {0.f, 0.f, 0.f, 0.f};

    // stage K (this head's 32 channels) into B-frag layout [key][40]
    for (int i = tid; i < 1408; i += 512) {
        int key = i >> 2, part = i & 3;
        *(short8*)(Ks + key * 40 + part * 8) =
            *(const short8*)(Kb + ((size_t)b * NPAD + key) * CEMB + h * 32 + part * 8);
    }
    // stage V^T (contiguous copy of this (b,h) plane)
    const unsigned short* vsrc = Vtb + (size_t)(b * NH + h) * 32 * 360;
    for (int i = tid; i < 1440; i += 512) {
        *(short8*)(Vt + i * 8) = *(const short8*)(vsrc + i * 8);
    }
    // per-wave Q A-frags straight from global
    short8 qa[3] = {};
#pragma unroll
    for (int i = 0; i < 3; i++) {
        int mt = wave + (i << 3);
        if (mt < 22)
            qa[i] = *(const short8*)(Qb + ((size_t)b * NPAD + mt * 16 + l16) * CEMB + h * 32 + (quad << 3));
    }
    __syncthreads();

    unsigned short* P = Pb + wave * 768;    // [16][48]
    const unsigned short* biasTp = biasT + (size_t)h * NPAD * NPAD;
    const unsigned short* maskTp = maskT + (size_t)(b & 63) * NPAD * NPAD;
#pragma unroll
    for (int i = 0; i < 3; i++) {
        int mt = wave + (i << 3);
        if (mt >= 22) continue;             // wave-uniform, no barriers below
        const int q0 = mt * 16 + (quad << 2);
        const unsigned short* bp = biasTp + q0;
        const unsigned short* mp = maskTp + q0;
        float rp[4] = {0.f, 0.f, 0.f, 0.f};
        f32x4 o0 = zero4, o1 = zero4;
        // preload bias/mask for chunk 0
        ushort4 cb0 = *(const ushort4*)(bp + (size_t)l16 * NPAD);
        ushort4 cm0 = *(const ushort4*)(mp + (size_t)l16 * NPAD);
        ushort4 cb1 = *(const ushort4*)(bp + (size_t)(16 + l16) * NPAD);
        ushort4 cm1 = *(const ushort4*)(mp + (size_t)(16 + l16) * NPAD);
        for (int ch = 0; ch < 11; ch++) {
            const int key0 = ch * 32 + l16;         // max 335 < 343: never padded
            const int key1 = key0 + 16;
            const short8 kb0 = *(const short8*)(Ks + key0 * 40 + (quad << 3));
            const short8 kb1 = *(const short8*)(Ks + key1 * 40 + (quad << 3));
            f32x4 s0 = __builtin_amdgcn_mfma_f32_16x16x32_bf16(qa[i], kb0, zero4, 0, 0, 0);
            f32x4 s1 = __builtin_amdgcn_mfma_f32_16x16x32_bf16(qa[i], kb1, zero4, 0, 0, 0);
            // prefetch bias/mask for next chunk
            int nc = (ch < 10) ? ch + 1 : 10;
            ushort4 nb0 = *(const ushort4*)(bp + (size_t)(nc * 32 + l16) * NPAD);
            ushort4 nm0 = *(const ushort4*)(mp + (size_t)(nc * 32 + l16) * NPAD);
            ushort4 nb1 = *(const ushort4*)(bp + (size_t)(nc * 32 + 16 + l16) * NPAD);
            ushort4 nm1 = *(const ushort4*)(mp + (size_t)(nc * 32 + 16 + l16) * NPAD);
            // t = 0
            float p0 = __expf(s0[0] + bf2f(cb0.x) + bf2f(cm0.x));
            float p1 = __expf(s0[1] + bf2f(cb0.y) + bf2f(cm0.y));
            float p2 = __expf(s0[2] + bf2f(cb0.z) + bf2f(cm0.z));
            float p3 = __expf(s0[3] + bf2f(cb0.w) + bf2f(cm0.w));
            rp[0] += p0; rp[1] += p1; rp[2] += p2; rp[3] += p3;
            unsigned short* pw0 = P + l16;
            pw0[((quad << 2) + 0) * 48] = f2bf(p0);
            pw0[((quad << 2) + 1) * 48] = f2bf(p1);
            pw0[((quad << 2) + 2) * 48] = f2bf(p2);
            pw0[((quad << 2) + 3) * 48] = f2bf(p3);
            // t = 1 (keys may be padded at ch=10)
            float q0f = __expf(s1[0] + bf2f(cb1.x) + bf2f(cm1.x));
            float q1f = __expf(s1[1] + bf2f(cb1.y) + bf2f(cm1.y));
            float q2f = __expf(s1[2] + bf2f(cb1.z) + bf2f(cm1.z));
            float q3f = __expf(s1[3] + bf2f(cb1.w) + bf2f(cm1.w));
            if (key1 >= NTOK) { q0f = 0.f; q1f = 0.f; q2f = 0.f; q3f = 0.f; }
            rp[0] += q0f; rp[1] += q1f; rp[2] += q2f; rp[3] += q3f;
            unsigned short* pw1 = P + 16 + l16;
            pw1[((quad << 2) + 0) * 48] = f2bf(q0f);
            pw1[((quad << 2) + 1) * 48] = f2bf(q1f);
            pw1[((quad << 2) + 2) * 48] = f2bf(q2f);
            pw1[((quad << 2) + 3) * 48] = f2bf(q3f);
            // PV for this chunk
            const short8 pa = *(const short8*)(P + l16 * 48 + (quad << 3));
            const short8 v0 = *(const short8*)(Vt + l16 * 360 + ch * 32 + (quad << 3));
            const short8 v1 = *(const short8*)(Vt + (16 + l16) * 360 + ch * 32 + (quad << 3));
            o0 = __builtin_amdgcn_mfma_f32_16x16x32_bf16(pa, v0, o0, 0, 0, 0);
            o1 = __builtin_amdgcn_mfma_f32_16x16x32_bf16(pa, v1, o1, 0, 0, 0);
            cb0 = nb0; cm0 = nm0; cb1 = nb1; cm1 = nm1;
        }
        // reduce row sums across the 16 col-lanes (xor bits 0..3 stay in-quad)
#pragma unroll
        for (int mm = 1; mm <= 8; mm <<= 1) {
            rp[0] += __shfl_xor(rp[0], mm);
            rp[1] += __shfl_xor(rp[1], mm);
            rp[2] += __shfl_xor(rp[2], mm);
            rp[3] += __shfl_xor(rp[3], mm);
        }
#pragma unroll
        for (int r = 0; r < 4; r++) {
            int n = mt * 16 + (quad << 2) + r;
            if (n < NTOK) {
                float inv = 1.f / rp[r];
                size_t base = ((size_t)b * NTOK + n) * CEMB + h * 32;
                attnb[base + l16] = f2bf(o0[r] * inv);
                attnb[base + 16 + l16] = f2bf(o1[r] * inv);
            }
        }
    }
}

// ---------------- output projection: out = attn @ proj_w^T + proj_b ----------------
__global__ __launch_bounds__(256, 4)
void proj_kernel(const unsigned short* __restrict__ attnb, const unsigned short* __restrict__ pwb,
                 const float* __restrict__ proj_b, float* __restrict__ out) {
    const int tid = threadIdx.x;
    const int wave = tid >> 6, lane = tid & 63;
    const int quad = lane >> 4, l16 = lane & 15;
    const int mt = blockIdx.x * 4 + wave;   // 5488 M-tiles total, exact
    const f32x4 zero4 = {0.f, 0.f, 0.f, 0.f};
    f32x4 acc[12];
#pragma unroll
    for (int nt = 0; nt < 12; nt++) acc[nt] = zero4;
#pragma unroll
    for (int ks = 0; ks < 6; ks++) {
        const short8 a = *(const short8*)(attnb + ((size_t)mt * 16 + l16) * CEMB + ks * 32 + (quad << 3));
#pragma unroll
        for (int nt = 0; nt < 12; nt++) {
            const short8 bfrag = *(const short8*)(pwb + ((size_t)(nt * 16 + l16)) * CEMB + ks * 32 + (quad << 3));
            acc[nt] = __builtin_amdgcn_mfma_f32_16x16x32_bf16(a, bfrag, acc[nt], 0, 0, 0);
        }
    }
#pragma unroll
    for (int nt = 0; nt < 12; nt++) {
        float bias = proj_b[nt * 16 + l16];
#pragma unroll
        for (int r = 0; r < 4; r++) {
            int m = mt * 16 + (quad << 2) + r;
            out[(size_t)m * CEMB + nt * 16 + l16] = acc[nt][r] + bias;
        }
    }
}

// ---------------- launch ----------------
extern "C" void kernel_launch(void* const* d_in, const int* in_sizes, int n_in,
                              void* d_out, int out_size, void* d_ws, size_t ws_size,
                              hipStream_t stream) {
    (void)in_sizes; (void)n_in; (void)out_size; (void)ws_size;
    const float* x_in    = (const float*)d_in[0];
    const float* x_cross = (const float*)d_in[1];
    const float* mask    = (const float*)d_in[2];
    const float* q_w     = (const float*)d_in[3];
    const float* kv_w    = (const float*)d_in[4];
    const float* proj_w  = (const float*)d_in[5];
    const float* proj_b  = (const float*)d_in[6];
    const float* btab    = (const float*)d_in[7];
    const int*   rel     = (const int*)d_in[8];
    float* out = (float*)d_out;
    char* ws = (char*)d_ws;

    // ws layout (bytes), total 155,955,200:
    unsigned short* qwb   = (unsigned short*)(ws + 0);           //     73,728
    unsigned short* kvwb  = (unsigned short*)(ws + 73728);       //    147,456
    unsigned short* pwb   = (unsigned short*)(ws + 221184);      //     73,728
    unsigned short* biasT = (unsigned short*)(ws + 294912);      //  1,486,848
    unsigned short* maskT = (unsigned short*)(ws + 1781760);     // 15,859,712
    unsigned short* attnb = (unsigned short*)(ws + 17641472);    // 33,718,272
    unsigned short* Qb    = (unsigned short*)(ws + 51359744);    // 34,603,008
    unsigned short* Kb    = (unsigned short*)(ws + 85962752);    // 34,603,008
    unsigned short* Vtb   = (unsigned short*)(ws + 120565760);   // 35,389,440

    prep_weights<<<576, 256, 0, stream>>>(q_w, kv_w, proj_w, qwb, kvwb, pwb);
    prep_biasT<<<121, 256, 0, stream>>>(btab, rel, biasT);
    prep_maskT<<<64 * 121, 256, 0, stream>>>(mask, maskT);
    qkv_kernel<<<NB * 6, 256, 0, stream>>>(x_in, x_cross, qwb, kvwb, Qb, Kb, Vtb);
    attn_kernel<<<NB * NH, 512, 63488, stream>>>(Qb, Kb, Vtb, biasT, maskT, attnb);
    proj_kernel<<<5488 / 4, 256, 0, stream>>>(attnb, pwb, proj_b, out);
}